// Round 6
// baseline (419.872 us; speedup 1.0000x reference)
//
#include <hip/hip_runtime.h>
#include <hip/hip_bf16.h>
#include <math.h>

// SGC: out = log_softmax( S^2 X W^T + b ), S = D^-1/2 (A+I) D^-1/2
// Classes split in two 20-class halves so each hop's gather buffer is 4 MB
// (= one XCD L2) -> row gathers become L2 hits. t rows are bf16, pre-scaled
// by dis. CSR built via bucketed counting sort (dense coalesced writes).

#define N_NODES 100000
#define N_FEAT  128
#define N_CLASS 40
#define HALF    20            // classes per split half

#define NB     512            // dst buckets
#define RANGE  196            // dst ids per bucket (ceil(100000/512))
#define CAP    7168           // max in-LDS records per bucket (mean 6250 + ~11 sigma)
#define P3GRID 1024           // scatter blocks (4/CU)

typedef __attribute__((ext_vector_type(8))) short short8;   // 8 bf16 (4 VGPRs)
typedef __attribute__((ext_vector_type(4))) float floatx4;  // MFMA C/D

// ---------------------------------------------------------------------------
// Edge-index: harness may hand us int32 or raw int64 words.
// If int64 (LE, values < 2^31), every odd 32-bit word is 0.
// Also zeroes bucketCount (merged launch).
__global__ void detect_zero_kernel(const int* __restrict__ ei, int* __restrict__ flag,
                                   int* __restrict__ bucketCount) {
    int t = threadIdx.x;                    // 512 threads
    if (t < NB) bucketCount[t] = 0;
    if (t < 64) {
        int nz = (ei[2 * t + 1] != 0) ? 1 : 0;
        unsigned long long b = __ballot(nz);
        if (t == 0) *flag = (b == 0ull) ? 1 : 0;   // 1 => int64 layout
    }
}

__device__ __forceinline__ int edge_word(const int* ei, int elem, int is64) {
    return is64 ? ei[2 * elem] : ei[elem];
}

// P1: per-bucket histogram, LDS-privatized.
__global__ __launch_bounds__(256) void p1_hist(
    const int* __restrict__ ei, int E, const int* __restrict__ flag,
    int* __restrict__ bucketCount)
{
    __shared__ int h[NB];
    for (int i = threadIdx.x; i < NB; i += 256) h[i] = 0;
    __syncthreads();
    int is64 = *flag;
    int stride = gridDim.x * 256;
    for (int e = blockIdx.x * 256 + threadIdx.x; e < E; e += stride) {
        int c = edge_word(ei, E + e, is64);
        atomicAdd(&h[c / RANGE], 1);
    }
    __syncthreads();
    for (int i = threadIdx.x; i < NB; i += 256)
        if (h[i]) atomicAdd(&bucketCount[i], h[i]);
}

// P2: scan bucket counts -> bucketStart/bucketCursor; starts[N]=E.
__global__ __launch_bounds__(NB) void p2_scan(
    const int* __restrict__ bucketCount, int* __restrict__ bucketStart,
    int* __restrict__ bucketCursor, int* __restrict__ starts, int E)
{
    __shared__ int s[NB];
    int t = threadIdx.x;
    int v = bucketCount[t];
    s[t] = v;
    __syncthreads();
    for (int o = 1; o < NB; o <<= 1) {
        int y = (t >= o) ? s[t - o] : 0;
        __syncthreads();
        s[t] += y;
        __syncthreads();
    }
    int incl = s[t], excl = incl - v;
    bucketStart[t] = excl;
    bucketCursor[t] = excl;
    if (t == NB - 1) { bucketStart[NB] = incl; starts[N_NODES] = E; }
}

// P3: chunked scatter of packed records (dstLocal<<24 | src) into per-block
// dense runs within each bucket (writes are line-coalesced).
__global__ __launch_bounds__(256) void p3_scatter(
    const int* __restrict__ ei, int E, const int* __restrict__ flag,
    int* __restrict__ bucketCursor, unsigned int* __restrict__ tmp)
{
    __shared__ int h[NB];
    __shared__ int base[NB];
    __shared__ int cur[NB];
    for (int i = threadIdx.x; i < NB; i += 256) h[i] = 0;
    __syncthreads();
    int is64 = *flag;
    int per = (E + gridDim.x - 1) / gridDim.x;
    int e0 = blockIdx.x * per;
    int e1 = min(E, e0 + per);
    for (int e = e0 + threadIdx.x; e < e1; e += 256) {
        int c = edge_word(ei, E + e, is64);
        atomicAdd(&h[c / RANGE], 1);
    }
    __syncthreads();
    for (int i = threadIdx.x; i < NB; i += 256) {
        base[i] = h[i] ? atomicAdd(&bucketCursor[i], h[i]) : 0;
        cur[i] = 0;
    }
    __syncthreads();
    for (int e = e0 + threadIdx.x; e < e1; e += 256) {
        int c = edge_word(ei, E + e, is64);
        int r = edge_word(ei, e, is64);
        int b = c / RANGE;
        int p = base[b] + atomicAdd(&cur[b], 1);
        tmp[p] = ((unsigned)(c - b * RANGE) << 24) | (unsigned)r;
    }
}

// P4: per-bucket LDS counting sort -> starts, dis, coalesced srcs.
__global__ __launch_bounds__(256) void p4_sort(
    const unsigned int* __restrict__ tmp, const int* __restrict__ bucketStart,
    int* __restrict__ starts, float* __restrict__ dis, int* __restrict__ srcs, int N)
{
    __shared__ unsigned int rec[CAP];
    __shared__ int srt[CAP];
    __shared__ int hist[256];
    __shared__ int sc[256];
    __shared__ int cur[256];
    int b = blockIdx.x, t = threadIdx.x;
    int g0 = b * RANGE;
    int gcnt = N - g0;
    if (gcnt > RANGE) gcnt = RANGE;
    if (gcnt < 0) gcnt = 0;
    int base = bucketStart[b];
    int n = bucketStart[b + 1] - base;
    hist[t] = 0;
    __syncthreads();
    bool inl = (n <= CAP);
    if (inl) {
        for (int i = t; i < n; i += 256) {
            unsigned v = tmp[base + i];
            rec[i] = v;
            atomicAdd(&hist[v >> 24], 1);
        }
    } else {
        for (int i = t; i < n; i += 256) {
            unsigned v = tmp[base + i];
            atomicAdd(&hist[v >> 24], 1);
        }
    }
    __syncthreads();
    int hv = hist[t];
    sc[t] = hv;
    __syncthreads();
    for (int o = 1; o < 256; o <<= 1) {
        int y = (t >= o) ? sc[t - o] : 0;
        __syncthreads();
        sc[t] += y;
        __syncthreads();
    }
    int excl = sc[t] - hv;
    if (t < gcnt) {
        starts[g0 + t] = base + excl;
        dis[g0 + t] = rsqrtf((float)(hv + 1));   // +1 self-loop
    }
    cur[t] = excl;
    __syncthreads();
    if (inl) {
        for (int i = t; i < n; i += 256) {
            unsigned v = rec[i];
            int p = atomicAdd(&cur[v >> 24], 1);
            srt[p] = (int)(v & 0xFFFFFFu);
        }
        __syncthreads();
        for (int i = t; i < n; i += 256) srcs[base + i] = srt[i];
    } else {
        // overflow fallback (statistically never taken): global re-read path
        for (int i = t; i < n; i += 256) {
            unsigned v = tmp[base + i];
            int p = atomicAdd(&cur[v >> 24], 1);
            srcs[base + p] = (int)(v & 0xFFFFFFu);
        }
    }
}

// ---------------------------------------------------------------------------
__device__ __forceinline__ unsigned short f2bf(float f) {   // RTN f32 -> bf16
    unsigned u = __float_as_uint(f);
    unsigned r = u + 0x7FFFu + ((u >> 16) & 1u);
    return (unsigned short)(r >> 16);
}
__device__ __forceinline__ float bf2f(unsigned short u) {
    return __uint_as_float(((unsigned)u) << 16);
}

// t0 = dis .* (X @ W^T), bf16, written as two class-halves (rows of 20).
// One wave per 16 nodes; MFMA 16x16x32 bf16.
__global__ __launch_bounds__(256) void transform_mfma(
    const float* __restrict__ x, const float* __restrict__ W,
    const float* __restrict__ dis,
    unsigned short* __restrict__ t0lo, unsigned short* __restrict__ t0hi, int N)
{
    __shared__ uint4 Wl[3 * 4 * 64];        // B frags, bf16-packed: 12 KiB
    int t = threadIdx.x;
    for (int i = t; i < 3 * 4 * 64; i += 256) {
        int lane = i & 63;
        int kc = (i >> 6) & 3;
        int nt = i >> 8;
        int n = nt * 16 + (lane & 15);
        int k = kc * 32 + (lane >> 4) * 8;
        union { unsigned short s[8]; uint4 v; } u;
        #pragma unroll
        for (int j = 0; j < 8; ++j)
            u.s[j] = (n < N_CLASS) ? f2bf(W[n * N_FEAT + k + j]) : (unsigned short)0;
        Wl[i] = u.v;
    }
    __syncthreads();
    int wave = (blockIdx.x * blockDim.x + threadIdx.x) >> 6;
    int lane = threadIdx.x & 63;
    int ntile = (N + 15) / 16;
    if (wave >= ntile) return;
    int m = lane & 15, quad = lane >> 4;
    int row = wave * 16 + m;                // N is a multiple of 16 (100000)
    const short8* Wf = reinterpret_cast<const short8*>(Wl);
    floatx4 acc0 = {0.f, 0.f, 0.f, 0.f}, acc1 = acc0, acc2 = acc0;
    #pragma unroll
    for (int kc = 0; kc < 4; ++kc) {
        const float4* xr = reinterpret_cast<const float4*>(
            x + (size_t)row * N_FEAT + kc * 32 + quad * 8);
        float4 a0 = xr[0], a1 = xr[1];
        short8 af;
        af[0] = f2bf(a0.x); af[1] = f2bf(a0.y); af[2] = f2bf(a0.z); af[3] = f2bf(a0.w);
        af[4] = f2bf(a1.x); af[5] = f2bf(a1.y); af[6] = f2bf(a1.z); af[7] = f2bf(a1.w);
        short8 b0 = Wf[(0 * 4 + kc) * 64 + lane];
        short8 b1 = Wf[(1 * 4 + kc) * 64 + lane];
        short8 b2 = Wf[(2 * 4 + kc) * 64 + lane];
        acc0 = __builtin_amdgcn_mfma_f32_16x16x32_bf16(af, b0, acc0, 0, 0, 0);
        acc1 = __builtin_amdgcn_mfma_f32_16x16x32_bf16(af, b1, acc1, 0, 0, 0);
        acc2 = __builtin_amdgcn_mfma_f32_16x16x32_bf16(af, b2, acc2, 0, 0, 0);
    }
    #pragma unroll
    for (int r = 0; r < 4; ++r) {
        int rw = wave * 16 + quad * 4 + r;
        float ds = dis[rw];
        size_t ro = (size_t)rw * HALF;
        // acc0: c = m (0..15) -> lo[m]
        t0lo[ro + m] = f2bf(ds * acc0[r]);
        // acc1: c = 16+m -> m<4: lo[16+m]; else hi[m-4]
        if (m < 4) t0lo[ro + 16 + m] = f2bf(ds * acc1[r]);
        else       t0hi[ro + (m - 4)] = f2bf(ds * acc1[r]);
        // acc2: c = 32+m (m<8) -> hi[12+m]
        if (m < 8) t0hi[ro + 12 + m] = f2bf(ds * acc2[r]);
    }
}

// Gather body over one 20-class half: 12 edges/iter (5 lanes x ushort4/edge).
// Accumulates t[d] + sum t[src] into a0..a3 of lanes 0-4 after the fold.
#define GATHER_HALF(tin)                                                        \
    int d = wave;                                                               \
    int g = lane / 5;                       /* 0..12 (lanes 60-63 ghost) */     \
    int sl = lane - g * 5;                  /* 0..4 */                          \
    int e0 = starts[d], e1 = starts[d + 1];                                     \
    float dd = dis[d];                                                          \
    float a0 = 0.f, a1 = 0.f, a2 = 0.f, a3 = 0.f;                               \
    if (lane < 5) {                         /* self term t[d] */                \
        ushort4 r = *reinterpret_cast<const ushort4*>((tin) + (size_t)d * HALF + lane * 4); \
        a0 = bf2f(r.x); a1 = bf2f(r.y); a2 = bf2f(r.z); a3 = bf2f(r.w);         \
    }                                                                           \
    int cnt = e1 - e0;                                                          \
    int full = cnt / 12;                                                        \
    int rem = cnt - full * 12;                                                  \
    int e = e0 + ((g < 12) ? g : 0);        /* ghosts trail group 0, unread */  \
    for (int it = 0; it < full; ++it) {                                         \
        int s = srcs[e];                                                        \
        ushort4 r = *reinterpret_cast<const ushort4*>((tin) + (size_t)s * HALF + sl * 4); \
        a0 += bf2f(r.x); a1 += bf2f(r.y); a2 += bf2f(r.z); a3 += bf2f(r.w);     \
        e += 12;                                                                \
    }                                                                           \
    if (g < rem) {                                                              \
        int s = srcs[e];                                                        \
        ushort4 r = *reinterpret_cast<const ushort4*>((tin) + (size_t)s * HALF + sl * 4); \
        a0 += bf2f(r.x); a1 += bf2f(r.y); a2 += bf2f(r.z); a3 += bf2f(r.w);     \
    }                                                                           \
    /* fold groups 12->1 (lanes 0-4 end correct; ghosts never read) */          \
    a0 += __shfl(a0, lane + 30); a1 += __shfl(a1, lane + 30);                   \
    a2 += __shfl(a2, lane + 30); a3 += __shfl(a3, lane + 30);                   \
    a0 += __shfl(a0, lane + 15); a1 += __shfl(a1, lane + 15);                   \
    a2 += __shfl(a2, lane + 15); a3 += __shfl(a3, lane + 15);                   \
    {                                                                           \
        float u0 = __shfl(a0, lane + 5), v0 = __shfl(a0, lane + 10);            \
        float u1 = __shfl(a1, lane + 5), v1 = __shfl(a1, lane + 10);            \
        float u2 = __shfl(a2, lane + 5), v2 = __shfl(a2, lane + 10);            \
        float u3 = __shfl(a3, lane + 5), v3 = __shfl(a3, lane + 10);            \
        a0 += u0 + v0; a1 += u1 + v1; a2 += u2 + v2; a3 += u3 + v3;             \
    }

// Middle hop on one half: tout[d] = dd^2 * (t[d] + sum t[src]), bf16.
__global__ __launch_bounds__(256) void prop_half_mid(
    const unsigned short* __restrict__ tin, unsigned short* __restrict__ tout,
    const int* __restrict__ starts, const int* __restrict__ srcs,
    const float* __restrict__ dis, int N)
{
    int wave = (blockIdx.x * blockDim.x + threadIdx.x) >> 6;
    int lane = threadIdx.x & 63;
    if (wave >= N) return;
    GATHER_HALF(tin)
    if (lane < 5) {
        float sc = dd * dd;
        ushort4 o;
        o.x = f2bf(sc * a0); o.y = f2bf(sc * a1);
        o.z = f2bf(sc * a2); o.w = f2bf(sc * a3);
        *reinterpret_cast<ushort4*>(tout + (size_t)d * HALF + lane * 4) = o;
    }
}

// Final hop on one half: z[d][halfoff + c] = dd * (t[d] + sum t[src]), f32.
__global__ __launch_bounds__(256) void prop_half_logit(
    const unsigned short* __restrict__ tin, float* __restrict__ z, int halfoff,
    const int* __restrict__ starts, const int* __restrict__ srcs,
    const float* __restrict__ dis, int N)
{
    int wave = (blockIdx.x * blockDim.x + threadIdx.x) >> 6;
    int lane = threadIdx.x & 63;
    if (wave >= N) return;
    GATHER_HALF(tin)
    if (lane < 5) {
        float4 o4 = make_float4(dd * a0, dd * a1, dd * a2, dd * a3);
        *reinterpret_cast<float4*>(z + (size_t)d * N_CLASS + halfoff + lane * 4) = o4;
    }
}

// In-place bias + log_softmax on z rows (z == d_out).
__global__ __launch_bounds__(256) void softmax_kernel(
    float* __restrict__ z, const float* __restrict__ bias, int N)
{
    int wave = (blockIdx.x * blockDim.x + threadIdx.x) >> 6;
    int lane = threadIdx.x & 63;
    if (wave >= N) return;
    int d = wave;
    int sl = (lane < 10) ? lane : 9;
    float4 v4;
    if (lane < 10) {
        v4 = reinterpret_cast<const float4*>(z + (size_t)d * N_CLASS)[lane];
        float4 b4 = reinterpret_cast<const float4*>(bias)[sl];
        v4.x += b4.x; v4.y += b4.y; v4.z += b4.z; v4.w += b4.w;
    } else {
        v4 = make_float4(-INFINITY, -INFINITY, -INFINITY, -INFINITY);
    }
    float mx = fmaxf(fmaxf(v4.x, v4.y), fmaxf(v4.z, v4.w));
    #pragma unroll
    for (int o = 8; o; o >>= 1) mx = fmaxf(mx, __shfl_xor(mx, o));
    float sum = (lane < 10)
        ? (expf(v4.x - mx) + expf(v4.y - mx) + expf(v4.z - mx) + expf(v4.w - mx)) : 0.f;
    #pragma unroll
    for (int o = 8; o; o >>= 1) sum += __shfl_xor(sum, o);
    if (lane < 10) {
        float ls = mx + logf(sum);
        float4 o4 = make_float4(v4.x - ls, v4.y - ls, v4.z - ls, v4.w - ls);
        reinterpret_cast<float4*>(z + (size_t)d * N_CLASS)[lane] = o4;
    }
}

// ---------------------------------------------------------------------------
extern "C" void kernel_launch(void* const* d_in, const int* in_sizes, int n_in,
                              void* d_out, int out_size, void* d_ws, size_t ws_size,
                              hipStream_t stream) {
    const float* feature = (const float*)d_in[0];   // [N, 128]
    const float* weight  = (const float*)d_in[1];   // [40, 128]
    const float* bias    = (const float*)d_in[2];   // [40]
    const int*   ei      = (const int*)d_in[3];     // [2, E] (int32 or int64 words)
    const int N = N_NODES;
    const int E = in_sizes[3] / 2;

    size_t off = 0;
    auto take = [&](size_t bytes) { size_t o = off; off += (bytes + 255) & ~(size_t)255; return o; };
    char* ws = (char*)d_ws;
    int*   flag    = (int*)  (ws + take(4));
    int*   bCount  = (int*)  (ws + take((size_t)NB * 4));
    int*   bStart  = (int*)  (ws + take((size_t)(NB + 1) * 4));
    int*   bCursor = (int*)  (ws + take((size_t)NB * 4));
    int*   starts  = (int*)  (ws + take((size_t)(N + 1) * 4));
    float* dis     = (float*)(ws + take((size_t)N * 4));
    int*   srcs    = (int*)  (ws + take((size_t)E * 4));
    // four contiguous 4 MB halves (lo0, hi0, lo1, hi1); tmp aliases all 16 MB
    unsigned short* t0lo = (unsigned short*)(ws + take((size_t)N * HALF * 2));
    unsigned short* t0hi = (unsigned short*)(ws + take((size_t)N * HALF * 2));
    unsigned short* t1lo = (unsigned short*)(ws + take((size_t)N * HALF * 2));
    unsigned short* t1hi = (unsigned short*)(ws + take((size_t)N * HALF * 2));
    unsigned int* tmp = (unsigned int*)t0lo;   // 16 MB span >= E*4; dead after p4
    float* z = (float*)d_out;                  // logits assembled here, softmax in place

    // --- build CSR (bucketed counting sort, coalesced writes) ---
    detect_zero_kernel<<<1, 512, 0, stream>>>(ei, flag, bCount);
    p1_hist<<<512, 256, 0, stream>>>(ei, E, flag, bCount);
    p2_scan<<<1, NB, 0, stream>>>(bCount, bStart, bCursor, starts, E);
    p3_scatter<<<P3GRID, 256, 0, stream>>>(ei, E, flag, bCursor, tmp);
    p4_sort<<<NB, 256, 0, stream>>>(tmp, bStart, starts, dis, srcs, N);

    // --- transform (MFMA, pre-scaled bf16 split halves) ---
    const int ntile = (N + 15) / 16;                       // 6250 row-tiles
    const int tblocks = (ntile * 64 + 255) / 256;
    transform_mfma<<<tblocks, 256, 0, stream>>>(feature, weight, dis, t0lo, t0hi, N);

    // --- two hops, class-split so gather buffer = 4 MB (one XCD L2) ---
    const int nodeBlocks = (N * 64 + 255) / 256;           // one wave per node
    prop_half_mid<<<nodeBlocks, 256, 0, stream>>>(t0lo, t1lo, starts, srcs, dis, N);
    prop_half_mid<<<nodeBlocks, 256, 0, stream>>>(t0hi, t1hi, starts, srcs, dis, N);
    prop_half_logit<<<nodeBlocks, 256, 0, stream>>>(t1lo, z, 0,    starts, srcs, dis, N);
    prop_half_logit<<<nodeBlocks, 256, 0, stream>>>(t1hi, z, HALF, starts, srcs, dis, N);
    softmax_kernel<<<nodeBlocks, 256, 0, stream>>>(z, bias, N);
}

// Round 7
// 364.781 us; speedup vs baseline: 1.1510x; 1.1510x over previous
//
#include <hip/hip_runtime.h>
#include <hip/hip_bf16.h>
#include <math.h>

// SGC: out = log_softmax( S^2 X W^T + b ), S = D^-1/2 (A+I) D^-1/2
// t0 = dis .* (X W^T) in bf16 (pre-scaled 80 B rows); each hop is
// y[d] = dis[d]*(t[d] + sum t[src]) with 6 row-gathers in flight per wave.
// CSR built via TWO-LEVEL bucketed counting sort: 64 coarse buckets (dense
// ~200 B runs) -> 512 fine buckets (dense ~3 KB runs) -> per-bucket LDS sort.

#define N_NODES 100000
#define N_FEAT  128
#define N_CLASS 40

#define NB      512           // fine dst buckets
#define RANGE   196           // dst ids per fine bucket (512*196 = 100352)
#define NC      64            // coarse buckets
#define RANGE_C 1568          // 8*RANGE; 64*1568 = 100352
#define CAP     7168          // fine records per bucket in LDS (mean 6250 + ~11 sigma)
#define CCAP    53248         // coarse region capacity (mean 50000 + ~14 sigma)
#define P3AGRID 1024

typedef __attribute__((ext_vector_type(8))) short short8;   // 8 bf16 (4 VGPRs)
typedef __attribute__((ext_vector_type(4))) float floatx4;  // MFMA C/D

// ---------------------------------------------------------------------------
// Detect int32 vs int64 edge_index words; zero counters. 1 block x 512.
__global__ void detect_zero_kernel(const int* __restrict__ ei, int* __restrict__ flag,
                                   int* __restrict__ bucketCount,
                                   int* __restrict__ coarseCnt) {
    int t = threadIdx.x;
    if (t < NB) bucketCount[t] = 0;
    if (t < NC) coarseCnt[t] = 0;
    if (t < 64) {
        int nz = (ei[2 * t + 1] != 0) ? 1 : 0;
        unsigned long long b = __ballot(nz);
        if (t == 0) *flag = (b == 0ull) ? 1 : 0;   // 1 => int64 layout
    }
}

__device__ __forceinline__ int edge_word(const int* ei, int elem, int is64) {
    return is64 ? ei[2 * elem] : ei[elem];
}

// P3a: scatter packed records (dstLocalCoarse<<17 | src) into per-block dense
// runs within 64 coarse regions; simultaneously build the 512-fine histogram.
__global__ __launch_bounds__(256) void p3a_scatter(
    const int* __restrict__ ei, int E, const int* __restrict__ flag,
    int* __restrict__ bucketCount, int* __restrict__ coarseCnt,
    unsigned int* __restrict__ tmpc)
{
    __shared__ int hf[NB];
    __shared__ int hc[NC];
    __shared__ int basec[NC];
    __shared__ int curc[NC];
    int t = threadIdx.x;
    for (int i = t; i < NB; i += 256) hf[i] = 0;
    if (t < NC) hc[t] = 0;
    __syncthreads();
    int is64 = *flag;
    int per = (E + gridDim.x - 1) / gridDim.x;
    int e0 = blockIdx.x * per;
    int e1 = min(E, e0 + per);
    for (int e = e0 + t; e < e1; e += 256) {
        int c = edge_word(ei, E + e, is64);
        atomicAdd(&hf[c / RANGE], 1);
        atomicAdd(&hc[c / RANGE_C], 1);
    }
    __syncthreads();
    if (t < NC) {
        basec[t] = hc[t] ? atomicAdd(&coarseCnt[t], hc[t]) : 0;
        curc[t] = 0;
    }
    for (int i = t; i < NB; i += 256)
        if (hf[i]) atomicAdd(&bucketCount[i], hf[i]);
    __syncthreads();
    for (int e = e0 + t; e < e1; e += 256) {
        int c = edge_word(ei, E + e, is64);
        int r = edge_word(ei, e, is64);
        int cb = c / RANGE_C;
        int p = basec[cb] + atomicAdd(&curc[cb], 1);
        if (p < CCAP)
            tmpc[(size_t)cb * CCAP + p] = ((unsigned)(c - cb * RANGE_C) << 17) | (unsigned)r;
    }
}

// P2: scan fine counts -> bucketStart/bucketCursor; starts[N]=E.
__global__ __launch_bounds__(NB) void p2_scan(
    const int* __restrict__ bucketCount, int* __restrict__ bucketStart,
    int* __restrict__ bucketCursor, int* __restrict__ starts, int E)
{
    __shared__ int s[NB];
    int t = threadIdx.x;
    int v = bucketCount[t];
    s[t] = v;
    __syncthreads();
    for (int o = 1; o < NB; o <<= 1) {
        int y = (t >= o) ? s[t - o] : 0;
        __syncthreads();
        s[t] += y;
        __syncthreads();
    }
    int incl = s[t], excl = incl - v;
    bucketStart[t] = excl;
    bucketCursor[t] = excl;
    if (t == NB - 1) { bucketStart[NB] = incl; starts[N_NODES] = E; }
}

// P3b: 8 blocks per coarse bucket; re-scatter into the 8 fine buckets.
// Writes are dense runs of ~780 records (~3 KB) -> amplification ~1.
__global__ __launch_bounds__(256) void p3b_scatter(
    const unsigned int* __restrict__ tmpc, const int* __restrict__ coarseCnt,
    int* __restrict__ bucketCursor, unsigned int* __restrict__ tmp)
{
    __shared__ int fh[8];
    __shared__ int fb[8];
    __shared__ int fc[8];
    int cb = blockIdx.x >> 3;
    int j = blockIdx.x & 7;
    int t = threadIdx.x;
    int cnt = coarseCnt[cb];
    if (cnt > CCAP) cnt = CCAP;
    int chunk = (cnt + 7) >> 3;
    int r0 = j * chunk;
    int r1 = min(cnt, r0 + chunk);
    if (t < 8) fh[t] = 0;
    __syncthreads();
    const unsigned int* rec = tmpc + (size_t)cb * CCAP;
    for (int i = r0 + t; i < r1; i += 256) {
        int dlc = (int)(rec[i] >> 17);
        atomicAdd(&fh[dlc / RANGE], 1);
    }
    __syncthreads();
    if (t < 8) {
        fb[t] = fh[t] ? atomicAdd(&bucketCursor[cb * 8 + t], fh[t]) : 0;
        fc[t] = 0;
    }
    __syncthreads();
    for (int i = r0 + t; i < r1; i += 256) {
        unsigned v = rec[i];
        int dlc = (int)(v >> 17);
        unsigned src = v & 0x1FFFFu;
        int fi = dlc / RANGE;
        int dlf = dlc - fi * RANGE;
        int p = fb[fi] + atomicAdd(&fc[fi], 1);
        tmp[p] = ((unsigned)dlf << 24) | src;
    }
}

// P4: per-fine-bucket LDS counting sort -> starts, dis, coalesced srcs.
__global__ __launch_bounds__(256) void p4_sort(
    const unsigned int* __restrict__ tmp, const int* __restrict__ bucketStart,
    int* __restrict__ starts, float* __restrict__ dis, int* __restrict__ srcs, int N)
{
    __shared__ unsigned int rec[CAP];
    __shared__ int srt[CAP];
    __shared__ int hist[256];
    __shared__ int sc[256];
    __shared__ int cur[256];
    int b = blockIdx.x, t = threadIdx.x;
    int g0 = b * RANGE;
    int gcnt = N - g0;
    if (gcnt > RANGE) gcnt = RANGE;
    if (gcnt < 0) gcnt = 0;
    int base = bucketStart[b];
    int n = bucketStart[b + 1] - base;
    hist[t] = 0;
    __syncthreads();
    bool inl = (n <= CAP);
    if (inl) {
        for (int i = t; i < n; i += 256) {
            unsigned v = tmp[base + i];
            rec[i] = v;
            atomicAdd(&hist[v >> 24], 1);
        }
    } else {
        for (int i = t; i < n; i += 256) {
            unsigned v = tmp[base + i];
            atomicAdd(&hist[v >> 24], 1);
        }
    }
    __syncthreads();
    int hv = hist[t];
    sc[t] = hv;
    __syncthreads();
    for (int o = 1; o < 256; o <<= 1) {
        int y = (t >= o) ? sc[t - o] : 0;
        __syncthreads();
        sc[t] += y;
        __syncthreads();
    }
    int excl = sc[t] - hv;
    if (t < gcnt) {
        starts[g0 + t] = base + excl;
        dis[g0 + t] = rsqrtf((float)(hv + 1));   // +1 self-loop
    }
    cur[t] = excl;
    __syncthreads();
    if (inl) {
        for (int i = t; i < n; i += 256) {
            unsigned v = rec[i];
            int p = atomicAdd(&cur[v >> 24], 1);
            srt[p] = (int)(v & 0xFFFFFFu);
        }
        __syncthreads();
        for (int i = t; i < n; i += 256) srcs[base + i] = srt[i];
    } else {
        for (int i = t; i < n; i += 256) {
            unsigned v = tmp[base + i];
            int p = atomicAdd(&cur[v >> 24], 1);
            srcs[base + p] = (int)(v & 0xFFFFFFu);
        }
    }
}

// ---------------------------------------------------------------------------
__device__ __forceinline__ unsigned short f2bf(float f) {   // RTN f32 -> bf16
    unsigned u = __float_as_uint(f);
    unsigned r = u + 0x7FFFu + ((u >> 16) & 1u);
    return (unsigned short)(r >> 16);
}
__device__ __forceinline__ float bf2f(unsigned short u) {
    return __uint_as_float(((unsigned)u) << 16);
}

// t0 = dis .* (X @ W^T), bf16, row stride 40 (80 B). One wave per 16 nodes.
__global__ __launch_bounds__(256) void transform_mfma(
    const float* __restrict__ x, const float* __restrict__ W,
    const float* __restrict__ dis, unsigned short* __restrict__ t0, int N)
{
    __shared__ uint4 Wl[3 * 4 * 64];        // B frags, bf16-packed: 12 KiB
    int t = threadIdx.x;
    for (int i = t; i < 3 * 4 * 64; i += 256) {
        int lane = i & 63;
        int kc = (i >> 6) & 3;
        int nt = i >> 8;
        int n = nt * 16 + (lane & 15);
        int k = kc * 32 + (lane >> 4) * 8;
        union { unsigned short s[8]; uint4 v; } u;
        #pragma unroll
        for (int j = 0; j < 8; ++j)
            u.s[j] = (n < N_CLASS) ? f2bf(W[n * N_FEAT + k + j]) : (unsigned short)0;
        Wl[i] = u.v;
    }
    __syncthreads();
    int wave = (blockIdx.x * blockDim.x + threadIdx.x) >> 6;
    int lane = threadIdx.x & 63;
    int ntile = (N + 15) / 16;
    if (wave >= ntile) return;
    int m = lane & 15, quad = lane >> 4;
    int row = wave * 16 + m;
    const short8* Wf = reinterpret_cast<const short8*>(Wl);
    floatx4 acc0 = {0.f, 0.f, 0.f, 0.f}, acc1 = acc0, acc2 = acc0;
    #pragma unroll
    for (int kc = 0; kc < 4; ++kc) {
        const float4* xr = reinterpret_cast<const float4*>(
            x + (size_t)row * N_FEAT + kc * 32 + quad * 8);
        float4 a0 = xr[0], a1 = xr[1];
        short8 af;
        af[0] = f2bf(a0.x); af[1] = f2bf(a0.y); af[2] = f2bf(a0.z); af[3] = f2bf(a0.w);
        af[4] = f2bf(a1.x); af[5] = f2bf(a1.y); af[6] = f2bf(a1.z); af[7] = f2bf(a1.w);
        short8 b0 = Wf[(0 * 4 + kc) * 64 + lane];
        short8 b1 = Wf[(1 * 4 + kc) * 64 + lane];
        short8 b2 = Wf[(2 * 4 + kc) * 64 + lane];
        acc0 = __builtin_amdgcn_mfma_f32_16x16x32_bf16(af, b0, acc0, 0, 0, 0);
        acc1 = __builtin_amdgcn_mfma_f32_16x16x32_bf16(af, b1, acc1, 0, 0, 0);
        acc2 = __builtin_amdgcn_mfma_f32_16x16x32_bf16(af, b2, acc2, 0, 0, 0);
    }
    #pragma unroll
    for (int r = 0; r < 4; ++r) {
        int rw = wave * 16 + quad * 4 + r;
        float ds = dis[rw];
        unsigned short* tr = t0 + (size_t)rw * N_CLASS;
        tr[m] = f2bf(ds * acc0[r]);
        tr[16 + m] = f2bf(ds * acc1[r]);
        if (m < 8) tr[32 + m] = f2bf(ds * acc2[r]);
    }
}

// Hop (pre-scaled): tout[d] = dis[d]^2 * ( t[d] + sum_{e:col=d} t[src] ), bf16.
// 6 edges per wave: group g=lane/10 handles edge e+g; sub-lane sl holds 4 classes.
__global__ __launch_bounds__(256) void prop_hop_kernel(
    const unsigned short* __restrict__ tin, unsigned short* __restrict__ tout,
    const int* __restrict__ starts, const int* __restrict__ srcs,
    const float* __restrict__ dis, int N)
{
    int wave = (blockIdx.x * blockDim.x + threadIdx.x) >> 6;
    int lane = threadIdx.x & 63;
    if (wave >= N) return;
    int d = wave;
    int g = lane / 10;
    int sl = lane - g * 10;
    int e0 = starts[d], e1 = starts[d + 1];
    float dd = dis[d];
    float a0 = 0.f, a1 = 0.f, a2 = 0.f, a3 = 0.f;
    if (g == 0) {
        ushort4 r = *reinterpret_cast<const ushort4*>(tin + (size_t)d * N_CLASS + sl * 4);
        a0 = bf2f(r.x); a1 = bf2f(r.y); a2 = bf2f(r.z); a3 = bf2f(r.w);
    }
    for (int e = e0; e < e1; e += 6) {
        int ee = e + g;
        int s = srcs[min(ee, e1 - 1)];
        ushort4 r = *reinterpret_cast<const ushort4*>(tin + (size_t)s * N_CLASS + sl * 4);
        float mk = (ee < e1 && g < 6) ? 1.0f : 0.0f;
        a0 = fmaf(mk, bf2f(r.x), a0);
        a1 = fmaf(mk, bf2f(r.y), a1);
        a2 = fmaf(mk, bf2f(r.z), a2);
        a3 = fmaf(mk, bf2f(r.w), a3);
    }
    a0 += __shfl(a0, lane + 30); a1 += __shfl(a1, lane + 30);
    a2 += __shfl(a2, lane + 30); a3 += __shfl(a3, lane + 30);
    float u0 = __shfl(a0, lane + 10), v0 = __shfl(a0, lane + 20);
    float u1 = __shfl(a1, lane + 10), v1 = __shfl(a1, lane + 20);
    float u2 = __shfl(a2, lane + 10), v2 = __shfl(a2, lane + 20);
    float u3 = __shfl(a3, lane + 10), v3 = __shfl(a3, lane + 20);
    a0 += u0 + v0; a1 += u1 + v1; a2 += u2 + v2; a3 += u3 + v3;
    if (lane < 10) {
        float sc = dd * dd;
        ushort4 o;
        o.x = f2bf(sc * a0); o.y = f2bf(sc * a1);
        o.z = f2bf(sc * a2); o.w = f2bf(sc * a3);
        *reinterpret_cast<ushort4*>(tout + (size_t)d * N_CLASS + lane * 4) = o;
    }
}

// Final hop fused with bias + log_softmax.
__global__ __launch_bounds__(256) void prop_final_kernel(
    const unsigned short* __restrict__ tin, float* __restrict__ out,
    const int* __restrict__ starts, const int* __restrict__ srcs,
    const float* __restrict__ dis, const float* __restrict__ bias, int N)
{
    int wave = (blockIdx.x * blockDim.x + threadIdx.x) >> 6;
    int lane = threadIdx.x & 63;
    if (wave >= N) return;
    int d = wave;
    int g = lane / 10;
    int sl = lane - g * 10;
    int e0 = starts[d], e1 = starts[d + 1];
    float dd = dis[d];
    float a0 = 0.f, a1 = 0.f, a2 = 0.f, a3 = 0.f;
    if (g == 0) {
        ushort4 r = *reinterpret_cast<const ushort4*>(tin + (size_t)d * N_CLASS + sl * 4);
        a0 = bf2f(r.x); a1 = bf2f(r.y); a2 = bf2f(r.z); a3 = bf2f(r.w);
    }
    for (int e = e0; e < e1; e += 6) {
        int ee = e + g;
        int s = srcs[min(ee, e1 - 1)];
        ushort4 r = *reinterpret_cast<const ushort4*>(tin + (size_t)s * N_CLASS + sl * 4);
        float mk = (ee < e1 && g < 6) ? 1.0f : 0.0f;
        a0 = fmaf(mk, bf2f(r.x), a0);
        a1 = fmaf(mk, bf2f(r.y), a1);
        a2 = fmaf(mk, bf2f(r.z), a2);
        a3 = fmaf(mk, bf2f(r.w), a3);
    }
    a0 += __shfl(a0, lane + 30); a1 += __shfl(a1, lane + 30);
    a2 += __shfl(a2, lane + 30); a3 += __shfl(a3, lane + 30);
    float u0 = __shfl(a0, lane + 10), w0 = __shfl(a0, lane + 20);
    float u1 = __shfl(a1, lane + 10), w1 = __shfl(a1, lane + 20);
    float u2 = __shfl(a2, lane + 10), w2 = __shfl(a2, lane + 20);
    float u3 = __shfl(a3, lane + 10), w3 = __shfl(a3, lane + 20);
    a0 += u0 + w0; a1 += u1 + w1; a2 += u2 + w2; a3 += u3 + w3;
    float4 b4 = reinterpret_cast<const float4*>(bias)[sl];   // sl<10 always
    float v0_ = dd * a0 + b4.x, v1_ = dd * a1 + b4.y;
    float v2_ = dd * a2 + b4.z, v3_ = dd * a3 + b4.w;
    float mx = (lane < 10) ? fmaxf(fmaxf(v0_, v1_), fmaxf(v2_, v3_)) : -INFINITY;
    #pragma unroll
    for (int o = 8; o; o >>= 1) mx = fmaxf(mx, __shfl_xor(mx, o));
    float sum = (lane < 10)
        ? (expf(v0_ - mx) + expf(v1_ - mx) + expf(v2_ - mx) + expf(v3_ - mx)) : 0.f;
    #pragma unroll
    for (int o = 8; o; o >>= 1) sum += __shfl_xor(sum, o);
    if (lane < 10) {
        float ls = mx + logf(sum);
        float4 o4 = make_float4(v0_ - ls, v1_ - ls, v2_ - ls, v3_ - ls);
        reinterpret_cast<float4*>(out + (size_t)d * N_CLASS)[lane] = o4;
    }
}

// ---------------------------------------------------------------------------
extern "C" void kernel_launch(void* const* d_in, const int* in_sizes, int n_in,
                              void* d_out, int out_size, void* d_ws, size_t ws_size,
                              hipStream_t stream) {
    const float* feature = (const float*)d_in[0];   // [N, 128]
    const float* weight  = (const float*)d_in[1];   // [40, 128]
    const float* bias    = (const float*)d_in[2];   // [40]
    const int*   ei      = (const int*)d_in[3];     // [2, E] (int32 or int64 words)
    const int N = N_NODES;
    const int E = in_sizes[3] / 2;

    size_t off = 0;
    auto take = [&](size_t bytes) { size_t o = off; off += (bytes + 255) & ~(size_t)255; return o; };
    char* ws = (char*)d_ws;
    int*   flag      = (int*)  (ws + take(4));
    int*   bCount    = (int*)  (ws + take((size_t)NB * 4));
    int*   bStart    = (int*)  (ws + take((size_t)(NB + 1) * 4));
    int*   bCursor   = (int*)  (ws + take((size_t)NB * 4));
    int*   coarseCnt = (int*)  (ws + take((size_t)NC * 4));
    int*   starts    = (int*)  (ws + take((size_t)(N + 1) * 4));
    float* dis       = (float*)(ws + take((size_t)N * 4));
    // srcs region also hosts tmpc (coarse records): tmpc dead before p4 writes srcs
    size_t srcsBytes = (size_t)E * 4;
    size_t tmpcBytes = (size_t)NC * CCAP * 4;
    size_t bigBytes = srcsBytes > tmpcBytes ? srcsBytes : tmpcBytes;
    char* bigBase = ws + take(bigBytes);
    int* srcs = (int*)bigBase;
    unsigned int* tmpc = (unsigned int*)bigBase;
    // t0+t1 (16 MB contiguous) also host tmp (fine records, E*4 = 12.8 MB):
    // tmp dead after p4, t0 written by transform afterwards
    unsigned short* t0 = (unsigned short*)(ws + take((size_t)N * N_CLASS * 2));
    unsigned short* t1 = (unsigned short*)(ws + take((size_t)N * N_CLASS * 2));
    unsigned int* tmp = (unsigned int*)t0;

    // --- build CSR (two-level bucketed counting sort) ---
    detect_zero_kernel<<<1, 512, 0, stream>>>(ei, flag, bCount, coarseCnt);
    p3a_scatter<<<P3AGRID, 256, 0, stream>>>(ei, E, flag, bCount, coarseCnt, tmpc);
    p2_scan<<<1, NB, 0, stream>>>(bCount, bStart, bCursor, starts, E);
    p3b_scatter<<<NC * 8, 256, 0, stream>>>(tmpc, coarseCnt, bCursor, tmp);
    p4_sort<<<NB, 256, 0, stream>>>(tmp, bStart, starts, dis, srcs, N);

    // --- transform (MFMA, pre-scaled bf16 rows) then 2 hops ---
    const int ntile = (N + 15) / 16;
    const int tblocks = (ntile * 64 + 255) / 256;
    transform_mfma<<<tblocks, 256, 0, stream>>>(feature, weight, dis, t0, N);
    const int nodeBlocks = (N * 64 + 255) / 256;           // one wave per node
    prop_hop_kernel<<<nodeBlocks, 256, 0, stream>>>(t0, t1, starts, srcs, dis, N);
    prop_final_kernel<<<nodeBlocks, 256, 0, stream>>>(t1, (float*)d_out,
                                                      starts, srcs, dis, bias, N);
}